// Round 1
// baseline (390.449 us; speedup 1.0000x reference)
//
#include <hip/hip_runtime.h>
#include <math.h>

// E-Langevin sampler, fully fused: one kernel runs all 5 scan steps.
//  * rows independent -> one wave owns one row for the whole scan
//  * x binary -> x@W is a gather-sum of W rows; x_delta@W is an
//    incremental sparse update (~19.5 flipped bits/row/step)
//  * NEW: W rows [0,128) cached in 128 KiB LDS (bit-exact copy).
//    d = 4j+i < 128  <=>  j < 32, so lo/hi = the two u32 halves of the
//    ballot mask; processing lo (LDS) ascending then hi (L2) ascending
//    preserves the EXACT ascending-d accumulation order of the passing
//    kernel -> bitwise-identical y/y2 -> absmax must stay 0.
//    This halves the ~3.7 GB L2 gather traffic (was ~16 TB/s, ~45% of
//    the L2 ceiling) and serves it at LDS latency instead.
//  * NEW: hi-row global loads are issued ahead of independent work
//    (init: before the LDS half; steps: before the logf pass) so L2
//    latency hides under VALU. Pure scheduling; no arithmetic change.
//  * gather accumulates packed as 2xfp32 (v_pk_add_f32 / v_pk_fma_f32):
//    identical rounding to scalar add/fmaf, half the VALU instructions
//  * rr/noise/x/xa loads and out stores are non-temporal so the ~200MB
//    streaming traffic does not evict W (256KB) from the XCD L2s
//  * accumulation order strictly ascending bit order per i-group --
//    bitwise identical to all passing rounds (absmax must stay 0)

namespace {

constexpr int kB = 16384;
constexpr int kD = 256;
constexpr int kSteps = 5;
constexpr int kLdsRows = 128;  // W rows [0,128) in LDS = 128*256*4 = 131072 B
constexpr int kWaves = 16;     // 16 waves (rows) per 1024-thread block

typedef float v2f __attribute__((ext_vector_type(2)));
typedef float v4f __attribute__((ext_vector_type(4)));

__device__ __forceinline__ v4f nt_load4(const float* p) {
  return __builtin_nontemporal_load(reinterpret_cast<const v4f*>(p));
}
__device__ __forceinline__ void nt_store4(float* p, v4f v) {
  __builtin_nontemporal_store(v, reinterpret_cast<v4f*>(p));
}

__device__ __forceinline__ float wave_sum(float v) {
#pragma unroll
  for (int off = 32; off > 0; off >>= 1) v += __shfl_xor(v, off, 64);
  return v;
}

__device__ __forceinline__ float sigmoid_f(float t) {
  if (t >= 0.0f) {
    float e = expf(-t);
    return 1.0f / (1.0f + e);
  } else {
    float e = expf(t);
    return e / (1.0f + e);
  }
}

__global__ __launch_bounds__(1024) void els_fused(
    const float* __restrict__ x_in, const float* __restrict__ xa_in,
    const float* __restrict__ W, const float* __restrict__ bvec,
    const float* __restrict__ rr, const float* __restrict__ noise,
    const float* __restrict__ accept_u, float* __restrict__ out) {
  __shared__ float wlds[kLdsRows * kD];  // 131072 B -> 1 block/CU, 16 waves

  const int tid = threadIdx.x;
  const int lane = tid & 63;
  const int row = blockIdx.x * kWaves + (tid >> 6);
  const int c0 = lane << 2;  // this lane owns columns c0..c0+3

  // per-row streaming loads issued first: latency overlaps the LDS fill
  const v4f x4 = nt_load4(x_in + (size_t)row * kD + c0);
  const v4f a4 = nt_load4(xa_in + (size_t)row * kD + c0);
  const float4 b4 = *reinterpret_cast<const float4*>(bvec + c0);
  v4f r4 = nt_load4(rr + (size_t)row * kD + c0);
  v4f n4 = nt_load4(noise + (size_t)row * kD + c0);
  float u = accept_u[row];

  // ---- cooperative bit-exact copy of W rows [0,128) into LDS ----
  {
    const float4* __restrict__ wsrc = reinterpret_cast<const float4*>(W);
    float4* wdst = reinterpret_cast<float4*>(wlds);
#pragma unroll
    for (int k = 0; k < (kLdsRows * kD / 4) / 1024; ++k)
      wdst[k * 1024 + tid] = wsrc[k * 1024 + tid];
  }
  __syncthreads();

  float xv[4] = {x4.x, x4.y, x4.z, x4.w};
  float xa[4] = {a4.x, a4.y, a4.z, a4.w};
  const float bv[4] = {b4.x, b4.y, b4.z, b4.w};
  v2f y01 = {0.0f, 0.0f}, y23 = {0.0f, 0.0f};

  // ---- init: y = x @ W. lo rows from LDS, hi rows from L2.
  //      accumulation order (i asc, j asc) identical to baseline ----
#pragma unroll
  for (int i = 0; i < 4; ++i) {
    const unsigned long long m = __ballot(xv[i] > 0.5f);
    const unsigned long long mlo = m & 0xffffffffull;
    unsigned long long mh = m & 0xffffffff00000000ull;
    const int hcnt = __popcll(mh);

    // issue first 8 hi loads now; they fly while the LDS half accumulates
    float4 hwp[8];
    const bool pre8 = hcnt >= 8;  // wave-uniform
    if (pre8) {
#pragma unroll
      for (int q = 0; q < 8; ++q) {
        const int j = __builtin_ctzll(mh); mh &= mh - 1;
        hwp[q] = *reinterpret_cast<const float4*>(W + (size_t)(4 * j + i) * kD + c0);
      }
    }

    // lo half from LDS, ascending, 8-wide batches
    {
      unsigned long long ml = mlo;
      const int cnt = __popcll(mlo);
      int t = 0;
      for (; t + 8 <= cnt; t += 8) {
        int j[8];
#pragma unroll
        for (int q = 0; q < 8; ++q) { j[q] = __builtin_ctzll(ml); ml &= ml - 1; }
        float4 w[8];
#pragma unroll
        for (int q = 0; q < 8; ++q)
          w[q] = *reinterpret_cast<const float4*>(&wlds[(4 * j[q] + i) * kD + c0]);
#pragma unroll
        for (int q = 0; q < 8; ++q) {
          y01 += (v2f){w[q].x, w[q].y};
          y23 += (v2f){w[q].z, w[q].w};
        }
      }
      for (; t < cnt; ++t) {
        const int jj = __builtin_ctzll(ml); ml &= ml - 1;
        const float4 w = *reinterpret_cast<const float4*>(&wlds[(4 * jj + i) * kD + c0]);
        y01 += (v2f){w.x, w.y};
        y23 += (v2f){w.z, w.w};
      }
    }

    // hi half: consume prefetch, then finish from global (still ascending)
    int t = 0;
    if (pre8) {
#pragma unroll
      for (int q = 0; q < 8; ++q) {
        y01 += (v2f){hwp[q].x, hwp[q].y};
        y23 += (v2f){hwp[q].z, hwp[q].w};
      }
      t = 8;
    }
    for (; t + 8 <= hcnt; t += 8) {
      int j[8];
#pragma unroll
      for (int q = 0; q < 8; ++q) { j[q] = __builtin_ctzll(mh); mh &= mh - 1; }
      float4 w[8];
#pragma unroll
      for (int q = 0; q < 8; ++q)
        w[q] = *reinterpret_cast<const float4*>(W + (size_t)(4 * j[q] + i) * kD + c0);
#pragma unroll
      for (int q = 0; q < 8; ++q) {
        y01 += (v2f){w[q].x, w[q].y};
        y23 += (v2f){w[q].z, w[q].w};
      }
    }
    for (; t < hcnt; ++t) {
      const int jj = __builtin_ctzll(mh); mh &= mh - 1;
      const float4 w = *reinterpret_cast<const float4*>(W + (size_t)(4 * jj + i) * kD + c0);
      y01 += (v2f){w.x, w.y};
      y23 += (v2f){w.z, w.w};
    }
  }

  for (int step = 0; step < kSteps; ++step) {
    // consume this step's prefetched inputs
    const float rrv[4] = {r4.x, r4.y, r4.z, r4.w};
    const float nzv[4] = {n4.x, n4.y, n4.z, n4.w};
    const float ucur = u;

    // prefetch NEXT step's inputs (issued now, consumed next iteration)
    const int sn = (step + 1 < kSteps) ? step + 1 : step;
    const size_t offn = ((size_t)sn * kB + row) * kD + c0;
    r4 = nt_load4(rr + offn);
    n4 = nt_load4(noise + offn);
    u = accept_u[(size_t)sn * kB + row];

    const float yv[4] = {y01.x, y01.y, y23.x, y23.y};
    float ga[4], xd[4], xda[4], pr[4];
    bool ind[4];
    unsigned long long fm[4], sm[4];

    // pass A: flip decisions + proposals (no logf here; values identical)
#pragma unroll
    for (int i = 0; i < 4; ++i) {
      ga[i] = (xv[i] - xa[i]) / 1.0e4f;                 // agrad, ETA=1e4
      const float sgn = 1.0f - 2.0f * xv[i];            // -(2x-1)
      const float gm = (yv[i] + bv[i] - ga[i]) * sgn / 2.0f;  // TEMP=2
      const float p = sigmoid_f(gm - 2.5f);             // term2 = 1/(2*0.2)
      ind[i] = rrv[i] < p;
      xd[i] = ind[i] ? 1.0f - xv[i] : xv[i];
      xda[i] = xa[i] + 0.25f * ga[i] + 0.70710678118654752f * nzv[i];
      pr[i] = ind[i] ? p : 1.0f - p;
      fm[i] = __ballot(ind[i]);
      sm[i] = __ballot(xv[i] > 0.5f);  // flip 1->0 subtracts the W row
    }

    // issue up to 2 hi-row L2 loads per i-group NOW; they fly under pass B
    unsigned long long mh_rem[4];
    int hcnt[4], hpre[4];
    float4 hw[4][2];
    float hs[4][2];
#pragma unroll
    for (int i = 0; i < 4; ++i) {
      unsigned long long mh = fm[i] & 0xffffffff00000000ull;
      hcnt[i] = __popcll(mh);
      const int np = hcnt[i] < 2 ? hcnt[i] : 2;
#pragma unroll
      for (int q = 0; q < 2; ++q) {
        if (q < np) {
          const int j = __builtin_ctzll(mh); mh &= mh - 1;
          hs[i][q] = ((sm[i] >> j) & 1ull) ? -1.0f : 1.0f;
          hw[i][q] = *reinterpret_cast<const float4*>(W + (size_t)(4 * j + i) * kD + c0);
        }
      }
      mh_rem[i] = mh;
      hpre[i] = np;
    }

    // pass B: logf + quadratic sums, same per-i accumulation order
    float s_lpf = 0.f, s_xy = 0.f, s_xb = 0.f, s_sqc = 0.f, s_fwd = 0.f;
#pragma unroll
    for (int i = 0; i < 4; ++i) {
      s_lpf += logf(pr[i] + 1e-10f);
      s_xy += xv[i] * yv[i];
      s_xb += xv[i] * bv[i];
      const float dc = xv[i] - xa[i];
      s_sqc += dc * dc;
      const float fw = xda[i] - (xa[i] + 0.25f * ga[i]);
      s_fwd += fw * fw;
    }

    // ---- y2 = x_delta @ W via sparse update over flipped bits.
    //      lo bits (j<32 -> d<128) from LDS, hi bits from L2;
    //      order per i-group: lo ascending then hi ascending == d asc ----
    v2f y2lo = y01, y2hi = y23;
#pragma unroll
    for (int i = 0; i < 4; ++i) {
      // lo half from LDS (4-wide + tail, ascending)
      {
        unsigned long long ml = fm[i] & 0xffffffffull;
        const int cnt = __popcll(ml);
        int t = 0;
        for (; t + 4 <= cnt; t += 4) {
          int j[4];
#pragma unroll
          for (int q = 0; q < 4; ++q) { j[q] = __builtin_ctzll(ml); ml &= ml - 1; }
          float4 w[4];
          float s[4];
#pragma unroll
          for (int q = 0; q < 4; ++q) {
            s[q] = ((sm[i] >> j[q]) & 1ull) ? -1.0f : 1.0f;
            w[q] = *reinterpret_cast<const float4*>(&wlds[(4 * j[q] + i) * kD + c0]);
          }
#pragma unroll
          for (int q = 0; q < 4; ++q) {
            const v2f sv = {s[q], s[q]};
            y2lo = __builtin_elementwise_fma(sv, (v2f){w[q].x, w[q].y}, y2lo);
            y2hi = __builtin_elementwise_fma(sv, (v2f){w[q].z, w[q].w}, y2hi);
          }
        }
        for (; t < cnt; ++t) {
          const int jj = __builtin_ctzll(ml); ml &= ml - 1;
          const float s = ((sm[i] >> jj) & 1ull) ? -1.0f : 1.0f;
          const float4 w = *reinterpret_cast<const float4*>(&wlds[(4 * jj + i) * kD + c0]);
          const v2f sv = {s, s};
          y2lo = __builtin_elementwise_fma(sv, (v2f){w.x, w.y}, y2lo);
          y2hi = __builtin_elementwise_fma(sv, (v2f){w.z, w.w}, y2hi);
        }
      }

      // hi half: prefetched rows first (lowest bits), then remainder
#pragma unroll
      for (int q = 0; q < 2; ++q) {
        if (q < hpre[i]) {
          const v2f sv = {hs[i][q], hs[i][q]};
          y2lo = __builtin_elementwise_fma(sv, (v2f){hw[i][q].x, hw[i][q].y}, y2lo);
          y2hi = __builtin_elementwise_fma(sv, (v2f){hw[i][q].z, hw[i][q].w}, y2hi);
        }
      }
      {
        unsigned long long mh = mh_rem[i];
        const int hc = hcnt[i];
        int t = hpre[i];
        for (; t + 4 <= hc; t += 4) {
          int j[4];
#pragma unroll
          for (int q = 0; q < 4; ++q) { j[q] = __builtin_ctzll(mh); mh &= mh - 1; }
          float4 w[4];
          float s[4];
#pragma unroll
          for (int q = 0; q < 4; ++q) {
            s[q] = ((sm[i] >> j[q]) & 1ull) ? -1.0f : 1.0f;
            w[q] = *reinterpret_cast<const float4*>(W + (size_t)(4 * j[q] + i) * kD + c0);
          }
#pragma unroll
          for (int q = 0; q < 4; ++q) {
            const v2f sv = {s[q], s[q]};
            y2lo = __builtin_elementwise_fma(sv, (v2f){w[q].x, w[q].y}, y2lo);
            y2hi = __builtin_elementwise_fma(sv, (v2f){w[q].z, w[q].w}, y2hi);
          }
        }
        for (; t < hc; ++t) {
          const int jj = __builtin_ctzll(mh); mh &= mh - 1;
          const float s = ((sm[i] >> jj) & 1ull) ? -1.0f : 1.0f;
          const float4 w = *reinterpret_cast<const float4*>(W + (size_t)(4 * jj + i) * kD + c0);
          const v2f sv = {s, s};
          y2lo = __builtin_elementwise_fma(sv, (v2f){w.x, w.y}, y2lo);
          y2hi = __builtin_elementwise_fma(sv, (v2f){w.z, w.w}, y2hi);
        }
      }
    }

    const float y2v[4] = {y2lo.x, y2lo.y, y2hi.x, y2hi.y};
    float s_lpr = 0.f, s_xdy = 0.f, s_xdb = 0.f, s_sqn = 0.f, s_rev = 0.f;
#pragma unroll
    for (int i = 0; i < 4; ++i) {
      const float ga2 = (xd[i] - xda[i]) / 1.0e4f;
      const float sgn2 = 1.0f - 2.0f * xd[i];
      const float gm2 = (y2v[i] + bv[i] - ga2) * sgn2 / 2.0f;
      const float p2 = sigmoid_f(gm2 - 2.5f);
      const float pr2 = ind[i] ? p2 : 1.0f - p2;
      s_lpr += logf(pr2 + 1e-10f);
      s_xdy += xd[i] * y2v[i];
      s_xdb += xd[i] * bv[i];
      const float dn = xd[i] - xda[i];
      s_sqn += dn * dn;
      const float rv = xa[i] - (xda[i] + 0.25f * ga2);
      s_rev += rv * rv;
    }

    // row reductions (wave = row)
    s_lpf = wave_sum(s_lpf);
    s_lpr = wave_sum(s_lpr);
    s_xy = wave_sum(s_xy);
    s_xb = wave_sum(s_xb);
    s_xdy = wave_sum(s_xdy);
    s_xdb = wave_sum(s_xdb);
    s_sqc = wave_sum(s_sqc);
    s_sqn = wave_sum(s_sqn);
    s_rev = wave_sum(s_rev);
    s_fwd = wave_sum(s_fwd);

    const float E_cur = 0.5f * s_xy + s_xb;
    const float E_new = 0.5f * s_xdy + s_xdb;
    const float m_term = (E_new - s_sqn / 2.0e4f) - (E_cur - s_sqc / 2.0e4f);
    // add_rev = s_rev / (-2*ALPHA_A) = -s_rev ; add_fwd = -s_fwd
    const float la = m_term - s_rev + s_fwd + s_lpr - s_lpf;
    const bool acc = la > logf(ucur);

#pragma unroll
    for (int i = 0; i < 4; ++i) {
      xv[i] = acc ? xd[i] : xv[i];
      xa[i] = acc ? xda[i] : xa[i];
    }
    y01 = acc ? y2lo : y01;
    y23 = acc ? y2hi : y23;
  }

  const v4f ox = {xv[0], xv[1], xv[2], xv[3]};
  const v4f oa = {xa[0], xa[1], xa[2], xa[3]};
  nt_store4(out + (size_t)row * kD + c0, ox);
  nt_store4(out + (size_t)kB * kD + (size_t)row * kD + c0, oa);
}

}  // namespace

extern "C" void kernel_launch(void* const* d_in, const int* in_sizes, int n_in,
                              void* d_out, int out_size, void* d_ws, size_t ws_size,
                              hipStream_t stream) {
  const float* x = (const float*)d_in[0];
  const float* xa = (const float*)d_in[1];
  const float* W = (const float*)d_in[2];
  const float* b = (const float*)d_in[3];
  const float* rr = (const float*)d_in[4];
  const float* noise = (const float*)d_in[5];
  const float* au = (const float*)d_in[6];
  float* out = (float*)d_out;

  dim3 grid(kB / kWaves);
  dim3 block(1024);
  hipLaunchKernelGGL(els_fused, grid, block, 0, stream, x, xa, W, b, rr, noise,
                     au, out);
}